// Round 1
// baseline (10902.558 us; speedup 1.0000x reference)
//
#include <hip/hip_runtime.h>
#include <math.h>

#define K_     191
#define LD     192
#define N_     147456
#define MSUB   32
#define NSPLIT 16
#define NT     15

// db5 decomposition filters (pywt convention), f32 as in reference
__constant__ float c_lo[10] = {
  0.003335725285001549f, -0.012580751999015526f, -0.006241490213011705f,
  0.07757149384006515f,  -0.03224486958502952f, -0.24229488706619015f,
  0.13842814590110342f,   0.7243085284385744f,   0.6038292697974729f,
  0.160102397974125f };
__constant__ float c_hi[10] = {
  0.160102397974125f,    -0.6038292697974729f,   0.7243085284385744f,
 -0.13842814590110342f,  -0.24229488706619015f,  0.03224486958502952f,
  0.07757149384006515f,   0.006241490213011705f,-0.012580751999015526f,
 -0.003335725285001549f };

// ---------------- column sums of x (f64), for the regression mean ----------
__global__ __launch_bounds__(256) void k_colsum(const float* __restrict__ x,
                                                double* __restrict__ m)
{
  int t = threadIdx.x;
  long base = (long)blockIdx.x * 512;
  if (t < K_) {
    double s = 0.0;
    const float* p = x + base * K_ + t;
    for (int r = 0; r < 512; ++r) s += (double)p[(long)r * K_];
    atomicAdd(&m[t], s);
  }
}

// ---------------- rr = x^T x (f64 accumulate), upper tile pairs, split-K ---
__global__ __launch_bounds__(256) void k_rr(const float* __restrict__ x,
                                            double* __restrict__ rrp)
{
  int bid   = blockIdx.x;
  int split = bid % NSPLIT;
  int pair  = bid / NSPLIT;
  int bi = 0, p = pair;
  for (;;) { int cnt = 12 - bi; if (p < cnt) break; p -= cnt; ++bi; }
  int bj = bi + p;
  int tx = threadIdx.x & 15, ty = threadIdx.x >> 4;
  int i = bi * 16 + tx;
  int j = bj * 16 + ty;
  __shared__ float As[64][17], Bs[64][17];
  double acc = 0.0;
  const int chunk = N_ / NSPLIT;       // 9216
  long n0 = (long)split * chunk;
  for (int c0 = 0; c0 < chunk; c0 += 64) {
    for (int lidx = threadIdx.x; lidx < 64 * 16; lidx += 256) {
      int col = lidx & 15, row = lidx >> 4;
      long nrow = n0 + c0 + row;
      int ci = bi * 16 + col, cj = bj * 16 + col;
      As[row][col] = (ci < K_) ? x[nrow * K_ + ci] : 0.f;
      Bs[row][col] = (cj < K_) ? x[nrow * K_ + cj] : 0.f;
    }
    __syncthreads();
    #pragma unroll 8
    for (int r = 0; r < 64; ++r)
      acc += (double)As[r][tx] * (double)Bs[r][ty];
    __syncthreads();
  }
  if (i < K_ && j < K_)
    rrp[(size_t)split * K_ * K_ + (size_t)i * K_ + j] = acc;
}

// ---------------- one-block small linear algebra ---------------------------
// reduce rr; Cholesky(rr+1e-6 I); X=L^-1; rri=X^T X; omega/invsq/sq32; G; normv
__global__ __launch_bounds__(1024) void k_small(
    const double* __restrict__ rrp, const double* __restrict__ m,
    double* __restrict__ rr, double* __restrict__ A, double* __restrict__ X,
    double* __restrict__ rri, double* __restrict__ omega,
    double* __restrict__ invsq, float* __restrict__ sq32,
    float* __restrict__ normv, double* __restrict__ G)
{
  const int t = threadIdx.x;
  // 1. reduce split partials, symmetrize, build A = rr + 1e-6 I
  for (int idx = t; idx < K_ * K_; idx += 1024) {
    int i = idx / K_, j = idx - i * K_;
    if (i <= j) {
      double s = 0.0;
      for (int sp = 0; sp < NSPLIT; ++sp) s += rrp[(size_t)sp * K_ * K_ + idx];
      rr[i * LD + j] = s; rr[j * LD + i] = s;
      double a = (i == j) ? s + 1e-6 : s;
      A[i * LD + j] = a; A[j * LD + i] = a;
    }
  }
  __syncthreads();
  // 2. Cholesky, lower in-place (SPD, no pivoting)
  __shared__ double spiv;
  for (int k = 0; k < K_; ++k) {
    if (t == 0) { spiv = sqrt(A[k * LD + k]); A[k * LD + k] = spiv; }
    __syncthreads();
    double piv = spiv;
    for (int r = k + 1 + t; r < K_; r += 1024) A[r * LD + k] /= piv;
    __syncthreads();
    int nrem = K_ - 1 - k;
    int total = nrem * (nrem + 1) / 2;
    for (int idx = t; idx < total; idx += 1024) {
      int jj = (int)((sqrt(8.0 * idx + 1.0) - 1.0) * 0.5);
      while ((jj + 1) * (jj + 2) / 2 <= idx) ++jj;
      while (jj * (jj + 1) / 2 > idx) --jj;
      int r = k + 1 + jj;
      int c = k + 1 + (idx - jj * (jj + 1) / 2);
      A[r * LD + c] -= A[r * LD + k] * A[c * LD + k];
    }
    __syncthreads();
  }
  // 3. X = L^{-1} (one thread per column), zero the upper part
  if (t < K_) {
    int i = t;
    for (int r = 0; r < i; ++r) X[r * LD + i] = 0.0;
    X[i * LD + i] = 1.0 / A[i * LD + i];
    for (int r = i + 1; r < K_; ++r) {
      double s = 0.0;
      for (int p = i; p < r; ++p) s += A[r * LD + p] * X[p * LD + i];
      X[r * LD + i] = -s / A[r * LD + r];
    }
  }
  __syncthreads();
  // 4. rri = X^T X, LDS-tiled
  __shared__ double Xa[32][33], Xb[32][33];
  int ti = t & 31, tj = t >> 5;
  for (int TI = 0; TI < 6; ++TI) {
    for (int TJ = 0; TJ < 6; ++TJ) {
      double acc = 0.0;
      for (int R = 0; R < 192; R += 32) {
        int gi = TI * 32 + ti, gj = TJ * 32 + ti, gr = R + tj;
        Xa[tj][ti] = (gr < K_ && gi < K_) ? X[gr * LD + gi] : 0.0;
        Xb[tj][ti] = (gr < K_ && gj < K_) ? X[gr * LD + gj] : 0.0;
        __syncthreads();
        #pragma unroll
        for (int r = 0; r < 32; ++r) acc += Xa[r][ti] * Xb[r][tj];
        __syncthreads();
      }
      int oi = TI * 32 + ti, oj = TJ * 32 + tj;
      if (oi < K_ && oj < K_) rri[oi * LD + oj] = acc;
    }
  }
  __syncthreads();
  // 5. per-band variance via c_i = rri[:,i]/rri[i,i]   (exact betas identity)
  if (t < K_) {
    int i = t;
    double dii = rri[i * LD + i];
    double nrm2 = 0.0, zm = 0.0;
    for (int j = 0; j < K_; ++j) {
      double z = rri[j * LD + i];
      nrm2 += z * z;
      zm += z * m[j];
    }
    double q = (dii - 1e-6 * nrm2) / (dii * dii);
    double sm_ = zm / dii;
    double var = (q - sm_ * sm_ / (double)N_) / (double)(N_ - 1);
    double t1 = sqrt(var) + 1e-30;
    double om = t1 * t1;
    omega[i] = om;
    invsq[i] = 1.0 / sqrt(om);
    sq32[i] = sqrtf((float)om);
  }
  __syncthreads();
  // 6. G = D rr D (whitened Gram), analytic norm_v = sum_k rr[kk]/omega_k
  for (int idx = t; idx < K_ * K_; idx += 1024) {
    int i = idx / K_, j = idx - i * K_;
    G[i * LD + j] = rr[i * LD + j] * invsq[i] * invsq[j];
  }
  if (t == 0) {
    double s = 0.0;
    for (int i = 0; i < K_; ++i) s += rr[i * LD + i] * invsq[i] * invsq[i];
    *normv = (float)s;
  }
}

// ---------------- one-block subspace iteration, top-32 eigenpairs of G -----
__global__ __launch_bounds__(1024) void k_sub(
    const double* __restrict__ G, double* __restrict__ Q,
    double* __restrict__ Zb, const double* __restrict__ invsq,
    const float* __restrict__ sq32, float* __restrict__ W1,
    float* __restrict__ W2)
{
  const int t = threadIdx.x;
  __shared__ double shQ[K_ * MSUB];     // 48.9 KB
  __shared__ double shS[MSUB * 33];     // 8.45 KB
  __shared__ double cs_[16], sn_[16];
  __shared__ int pp_[16], qq_[16], perm[MSUB];
  __shared__ double evals[MSUB];

  // init Q = G[:, 0:32]
  for (int idx = t; idx < K_ * MSUB; idx += 1024) {
    int i = idx >> 5, c = idx & 31;
    Q[idx] = G[(size_t)i * LD + c];
  }
  __syncthreads();

  for (int it = 0; it < 6; ++it) {
    // stage Q
    for (int idx = t; idx < K_ * MSUB; idx += 1024) shQ[idx] = Q[idx];
    __syncthreads();
    // S = Q^T Q
    {
      int a = t & 31, b = t >> 5;
      double s = 0.0;
      for (int r = 0; r < K_; ++r) s += shQ[r * MSUB + a] * shQ[r * MSUB + b];
      shS[b * 33 + a] = s;
    }
    __syncthreads();
    // Cholesky of S in LDS (lower)
    for (int k = 0; k < MSUB; ++k) {
      if (t == 0) shS[k * 33 + k] = sqrt(shS[k * 33 + k]);
      __syncthreads();
      if (t > k && t < MSUB) shS[t * 33 + k] /= shS[k * 33 + k];
      __syncthreads();
      {
        int r = t & 31, c = t >> 5;
        if (c > k && r >= c) shS[r * 33 + c] -= shS[r * 33 + k] * shS[c * 33 + k];
      }
      __syncthreads();
    }
    // rows solve: Qnew L^T = Qold
    if (t < K_) {
      double q[MSUB];
      #pragma unroll
      for (int c = 0; c < MSUB; ++c) {
        double v = shQ[t * MSUB + c];
        for (int p = 0; p < c; ++p) v -= q[p] * shS[c * 33 + p];
        q[c] = v / shS[c * 33 + c];
      }
      #pragma unroll
      for (int c = 0; c < MSUB; ++c) { Q[t * MSUB + c] = q[c]; shQ[t * MSUB + c] = q[c]; }
    }
    __syncthreads();
    if (it < 5) {
      // Q <- G * Qorth
      for (int idx = t; idx < K_ * MSUB; idx += 1024) {
        int i = idx >> 5, c = idx & 31;
        double s = 0.0;
        for (int k2 = 0; k2 < K_; ++k2) s += G[(size_t)i * LD + k2] * shQ[k2 * MSUB + c];
        Q[idx] = s;
      }
      __syncthreads();
    }
  }
  // Zb = G * Q
  for (int idx = t; idx < K_ * MSUB; idx += 1024) {
    int i = idx >> 5, c = idx & 31;
    double s = 0.0;
    for (int k2 = 0; k2 < K_; ++k2) s += G[(size_t)i * LD + k2] * shQ[k2 * MSUB + c];
    Zb[idx] = s;
  }
  __syncthreads();
  // T = Q^T Zb  (into shS)
  {
    int a = t & 31, b = t >> 5;
    double s = 0.0;
    for (int r = 0; r < K_; ++r) s += shQ[r * MSUB + b] * Zb[r * MSUB + a];
    shS[b * 33 + a] = s;
  }
  __syncthreads();
  // Jacobi on 32x32 T (shS); eigenvectors Ws alias shQ (Q no longer needed in LDS)
  double* Ws = shQ;
  for (int idx = t; idx < MSUB * 33; idx += 1024) Ws[idx] = 0.0;
  __syncthreads();
  if (t < MSUB) Ws[t * 33 + t] = 1.0;
  __syncthreads();
  for (int sweep = 0; sweep < 7; ++sweep) {
    for (int round = 0; round < 31; ++round) {
      if (t < 16) {
        int ia = (t == 0) ? 0 : (1 + ((t - 1 + round) % 31));
        int ib = 1 + ((30 - t + round) % 31);
        int p = ia < ib ? ia : ib;
        int q = ia < ib ? ib : ia;
        double app = shS[p * 33 + p], aqq = shS[q * 33 + q], apq = shS[p * 33 + q];
        double c = 1.0, s = 0.0;
        if (fabs(apq) > 1e-30 * (fabs(app) + fabs(aqq)) && apq != 0.0) {
          double tau = (aqq - app) / (2.0 * apq);
          double tt = (tau >= 0.0 ? 1.0 : -1.0) / (fabs(tau) + sqrt(1.0 + tau * tau));
          c = 1.0 / sqrt(1.0 + tt * tt); s = tt * c;
        }
        cs_[t] = c; sn_[t] = s; pp_[t] = p; qq_[t] = q;
      }
      __syncthreads();
      if (t < 512) {   // column rotation of T and of Ws (disjoint arrays)
        int i = t & 31, mI = t >> 5;
        int p = pp_[mI], q = qq_[mI];
        double c = cs_[mI], s = sn_[mI];
        double u = shS[i * 33 + p], v = shS[i * 33 + q];
        shS[i * 33 + p] = c * u - s * v; shS[i * 33 + q] = s * u + c * v;
        double wu = Ws[i * 33 + p], wv = Ws[i * 33 + q];
        Ws[i * 33 + p] = c * wu - s * wv; Ws[i * 33 + q] = s * wu + c * wv;
      }
      __syncthreads();
      if (t < 512) {   // row rotation of T
        int j = t & 31, mI = t >> 5;
        int p = pp_[mI], q = qq_[mI];
        double c = cs_[mI], s = sn_[mI];
        double u = shS[p * 33 + j], v = shS[q * 33 + j];
        shS[p * 33 + j] = c * u - s * v; shS[q * 33 + j] = s * u + c * v;
      }
      __syncthreads();
    }
  }
  if (t == 0) {
    for (int i = 0; i < MSUB; ++i) { evals[i] = shS[i * 33 + i]; perm[i] = i; }
    for (int i = 0; i < MSUB; ++i) {
      int best = i;
      for (int j = i + 1; j < MSUB; ++j)
        if (evals[perm[j]] > evals[perm[best]]) best = j;
      int tmp = perm[i]; perm[i] = perm[best]; perm[best] = tmp;
    }
  }
  __syncthreads();
  // E = Q * W (sorted); emit W1[k][c] = invsq_k * E  and  W2[c][j] = E * sq32_j
  for (int idx = t; idx < K_ * MSUB; idx += 1024) {
    int i = idx >> 5, c = idx & 31;
    int pc_ = perm[c];
    double e = 0.0;
    for (int p = 0; p < MSUB; ++p) e += Q[i * MSUB + p] * Ws[p * 33 + pc_];
    W1[i * MSUB + c] = (float)(invsq[i] * e);
    W2[c * K_ + i]   = ((float)e) * sq32[i];
  }
}

// ---------------- pc = x * W1 (f32), channel-major output ------------------
__global__ __launch_bounds__(256) void k_pc(const float* __restrict__ x,
                                            const float* __restrict__ W1,
                                            float* __restrict__ pc)
{
  __shared__ float xs[32][192];            // 24.6 KB
  __shared__ float w1s[K_ * MSUB];         // 24.4 KB
  int t = threadIdx.x;
  long n0 = (long)blockIdx.x * 32;
  for (int idx = t; idx < K_ * MSUB; idx += 256) w1s[idx] = W1[idx];
  for (int idx = t; idx < 32 * K_; idx += 256) {
    int row = idx / K_, col = idx - row * K_;
    xs[row][col] = x[(n0 + row) * K_ + col];
  }
  __syncthreads();
  int c = t & 31, nl = t >> 5;             // nl in [0,8)
  float a0 = 0.f, a1 = 0.f, a2 = 0.f, a3 = 0.f;
  for (int k = 0; k < K_; ++k) {
    float w = w1s[k * MSUB + c];
    a0 += xs[nl][k] * w;
    a1 += xs[nl + 8][k] * w;
    a2 += xs[nl + 16][k] * w;
    a3 += xs[nl + 24][k] * w;
  }
  __syncthreads();
  float* ts = &xs[0][0];                   // reuse as 32x33 transpose buffer
  ts[c * 33 + nl]      = a0;
  ts[c * 33 + nl + 8]  = a1;
  ts[c * 33 + nl + 16] = a2;
  ts[c * 33 + nl + 24] = a3;
  __syncthreads();
  for (int idx = t; idx < 1024; idx += 256) {
    int cc = idx >> 5, nn = idx & 31;
    pc[(size_t)cc * N_ + n0 + nn] = ts[cc * 33 + nn];
  }
}

// ---------------- DWT: vertical analysis pass ------------------------------
__global__ __launch_bounds__(256) void k_dwtv(const float* __restrict__ in,
                                              float* __restrict__ outv, int s)
{
  long gid = (long)blockIdx.x * 256 + threadIdx.x;
  int h = s >> 1;
  long per = (long)h * s;
  if (gid >= 32 * per) return;
  int ch = (int)(gid / per);
  long rem = gid - (long)ch * per;
  int r = (int)(rem / s);
  int col = (int)(rem - (long)r * s);
  const float* cin = in + (long)ch * s * s;
  float la = 0.f, ld_ = 0.f;
  int base = 2 * r;
  #pragma unroll
  for (int l = 0; l < 10; ++l) {
    int rr_ = base + l; if (rr_ >= s) rr_ -= s;
    float v = cin[(long)rr_ * s + col];
    la += c_lo[l] * v; ld_ += c_hi[l] * v;
  }
  float* cout = outv + (long)ch * s * s;
  cout[(long)r * s + col] = la;
  cout[(long)(h + r) * s + col] = ld_;
}

// ---------------- DWT: horizontal analysis pass ----------------------------
__global__ __launch_bounds__(256) void k_dwth(const float* __restrict__ inv,
                                              float* __restrict__ llout,
                                              float* __restrict__ coef,
                                              int s, long offL, int last)
{
  long gid = (long)blockIdx.x * 256 + threadIdx.x;
  int h = s >> 1;
  long per = (long)s * h;
  if (gid >= 32 * per) return;
  int ch = (int)(gid / per);
  long rem = gid - (long)ch * per;
  int r = (int)(rem / h);
  int mcol = (int)(rem - (long)r * h);
  const float* row = inv + (long)ch * s * s + (long)r * s;
  float lo = 0.f, hi = 0.f;
  int base = 2 * mcol;
  #pragma unroll
  for (int l = 0; l < 10; ++l) {
    int cc = base + l; if (cc >= s) cc -= s;
    float v = row[cc];
    lo += c_lo[l] * v; hi += c_hi[l] * v;
  }
  float* cslab = coef + (size_t)ch * N_ + offL;
  if (r < h) {
    llout[(size_t)ch * h * h + (long)r * h + mcol] = lo;     // ll -> next level
    if (last) coef[(size_t)ch * N_ + 147312 + (long)r * h + mcol] = lo;
    cslab[(long)r * h + mcol] = hi;                          // lh
  } else {
    int rd = r - h;
    cslab[(long)h * h + (long)rd * h + mcol] = lo;           // hl
    cslab[(long)2 * h * h + (long)rd * h + mcol] = hi;       // hh
  }
}

// ---------------- SURE statistics per channel ------------------------------
__global__ __launch_bounds__(256) void k_stats(const float* __restrict__ coef,
                                               float* __restrict__ stats)
{
  int ch = blockIdx.x;
  int t = threadIdx.x;
  float T2[NT];
  {
    double stop = sqrt(log(147456.0));
    double step = stop / 14.0;
    for (int i = 0; i < NT; ++i) {
      double td = (i == 14) ? stop : (double)i * step;
      float tf = (float)td;
      T2[i] = tf * tf;
    }
  }
  float cn = 0.f, sm[NT], ct[NT];
  #pragma unroll
  for (int i = 0; i < NT; ++i) { sm[i] = 0.f; ct[i] = 0.f; }
  const float* base = coef + (size_t)ch * N_;
  for (int idx = t; idx < N_; idx += 256) {
    float v = base[idx];
    float v2 = v * v;
    cn += v2;
    #pragma unroll
    for (int i = 0; i < NT; ++i) {
      sm[i] += fminf(v2, T2[i]);
      ct[i] += (v2 > T2[i]) ? 1.0f : 0.0f;
    }
  }
  __shared__ float red[256];
  // reduce 31 accumulators sequentially (deterministic per channel)
  for (int a = 0; a < 31; ++a) {
    float val = (a == 0) ? cn : ((a < 16) ? sm[a - 1] : ct[a - 16]);
    red[t] = val;
    __syncthreads();
    for (int off = 128; off > 0; off >>= 1) {
      if (t < off) red[t] += red[t + off];
      __syncthreads();
    }
    if (t == 0) stats[ch * 31 + a] = red[0];
    __syncthreads();
  }
}

// ---------------- SURE scan + rank -----------------------------------------
__global__ void k_rank(const float* __restrict__ stats,
                       const float* __restrict__ normv, int* __restrict__ rankp)
{
  if (threadIdx.x != 0 || blockIdx.x != 0) return;
  float c_const = *normv - 28164096.0f;   // norm_v - N*K (exact in f32)
  float acc[NT];
  for (int i = 0; i < NT; ++i) acc[i] = 0.f;
  float minsure[MSUB];
  for (int r = 0; r < MSUB; ++r) {
    float cn = stats[r * 31 + 0];
    float mn = 3.4e38f;
    for (int i = 0; i < NT; ++i) {
      float sure = stats[r * 31 + 1 + i] + 2.0f * stats[r * 31 + 16 + i] - cn;
      float s_r = acc[i] + sure + c_const;
      acc[i] = acc[i] + s_r;
      if (s_r < mn) mn = s_r;
    }
    minsure[r] = mn;
  }
  int rank = -1;
  for (int r = 2; r < MSUB; ++r) {
    if (minsure[r] > minsure[r - 1]) { rank = r; break; }
  }
  if (rank < 0) rank = MSUB - 1;  // fallback (analysis says unreachable)
  *rankp = rank;
}

// ---------------- output: out = sqrt(omega) .* (pc[:, :rank] @ vh) ---------
__global__ __launch_bounds__(256) void k_out(const float* __restrict__ pc,
                                             const float* __restrict__ W2,
                                             const int* __restrict__ rankp,
                                             float* __restrict__ out)
{
  long gid = (long)blockIdx.x * 256 + threadIdx.x;
  int n = (int)(gid / K_);
  int j = (int)(gid - (long)n * K_);
  int rank = *rankp;
  float acc = 0.f;
  for (int c = 0; c < rank; ++c)
    acc += pc[(size_t)c * N_ + n] * W2[c * K_ + j];
  out[gid] = acc;
}

extern "C" void kernel_launch(void* const* d_in, const int* in_sizes, int n_in,
                              void* d_out, int out_size, void* d_ws, size_t ws_size,
                              hipStream_t stream)
{
  if (n_in < 1 || in_sizes[0] != N_ * K_) return;
  const float* x = (const float*)d_in[0];
  float* out = (float*)d_out;
  (void)out_size;

  char* w = (char*)d_ws;
  size_t off = 0;
  auto alloc = [&](size_t bytes) -> char* {
    char* p = w + off;
    off = (off + bytes + 255) & ~(size_t)255;
    return p;
  };
  double* m_    = (double*)alloc(K_ * 8);
  double* rrp   = (double*)alloc((size_t)NSPLIT * K_ * K_ * 8);
  double* rr    = (double*)alloc((size_t)K_ * LD * 8);
  double* A     = (double*)alloc((size_t)K_ * LD * 8);
  double* X     = (double*)alloc((size_t)K_ * LD * 8);
  double* rri   = (double*)alloc((size_t)K_ * LD * 8);
  double* omega = (double*)alloc(K_ * 8);
  double* invsq = (double*)alloc(K_ * 8);
  float*  sq32  = (float*)alloc(K_ * 4);
  float*  normv = (float*)alloc(256);
  double* G     = (double*)alloc((size_t)K_ * LD * 8);
  double* Q     = (double*)alloc((size_t)K_ * MSUB * 8);
  double* Zb    = (double*)alloc((size_t)K_ * MSUB * 8);
  float*  W1    = (float*)alloc((size_t)K_ * MSUB * 4);
  float*  W2    = (float*)alloc((size_t)MSUB * K_ * 4);
  float*  pc    = (float*)alloc((size_t)MSUB * N_ * 4);
  float*  tmpv  = (float*)alloc((size_t)MSUB * N_ * 4);
  float*  coef  = (float*)alloc((size_t)MSUB * N_ * 4);
  float*  curA  = (float*)alloc((size_t)MSUB * 192 * 192 * 4);
  float*  curB  = (float*)alloc((size_t)MSUB * 96 * 96 * 4);
  float*  stats = (float*)alloc((size_t)MSUB * 31 * 4);
  int*    rankp = (int*)alloc(256);
  if (off > ws_size) return;   // workspace too small -> visible failure

  hipMemsetAsync(m_, 0, K_ * sizeof(double), stream);

  k_colsum<<<N_ / 512, 256, 0, stream>>>(x, m_);
  k_rr<<<78 * NSPLIT, 256, 0, stream>>>(x, rrp);
  k_small<<<1, 1024, 0, stream>>>(rrp, m_, rr, A, X, rri, omega, invsq,
                                  sq32, normv, G);
  k_sub<<<1, 1024, 0, stream>>>(G, Q, Zb, invsq, sq32, W1, W2);
  k_pc<<<N_ / 32, 256, 0, stream>>>(x, W1, pc);

  // 5-level 2D DWT (vertical then horizontal, periodized, forward only)
  int   sizes[5] = {384, 192, 96, 48, 24};
  long  offs[5]  = {0, 110592, 138240, 145152, 146880};
  float* lls[5]  = {curA, curB, curA, curB, curA};
  const float* curin = pc;
  for (int lev = 0; lev < 5; ++lev) {
    int s = sizes[lev], h = s >> 1;
    int nth = 32 * h * s;
    k_dwtv<<<nth / 256, 256, 0, stream>>>(curin, tmpv, s);
    k_dwth<<<nth / 256, 256, 0, stream>>>(tmpv, lls[lev], coef, s, offs[lev],
                                          lev == 4 ? 1 : 0);
    curin = lls[lev];
  }

  k_stats<<<MSUB, 256, 0, stream>>>(coef, stats);
  k_rank<<<1, 64, 0, stream>>>(stats, normv, rankp);
  k_out<<<(N_ * K_) / 256, 256, 0, stream>>>(pc, W2, rankp, out);
}

// Round 2
// 2605.268 us; speedup vs baseline: 4.1848x; 4.1848x over previous
//
#include <hip/hip_runtime.h>
#include <math.h>

#define K_     191
#define LD     192
#define N_     147456
#define MSUB   32
#define NSPLIT 16
#define NT     15
#define TRI_N  18336   // 191*192/2
#define SMEM_SZ ((TRI_N + 192 + 192 + 1056) * 8)

// db5 decomposition filters (pywt convention), f32 as in reference
__constant__ float c_lo[10] = {
  0.003335725285001549f, -0.012580751999015526f, -0.006241490213011705f,
  0.07757149384006515f,  -0.03224486958502952f, -0.24229488706619015f,
  0.13842814590110342f,   0.7243085284385744f,   0.6038292697974729f,
  0.160102397974125f };
__constant__ float c_hi[10] = {
  0.160102397974125f,    -0.6038292697974729f,   0.7243085284385744f,
 -0.13842814590110342f,  -0.24229488706619015f,  0.03224486958502952f,
  0.07757149384006515f,   0.006241490213011705f,-0.012580751999015526f,
 -0.003335725285001549f };

// ---------------- column sums of x (f64), for the regression mean ----------
__global__ __launch_bounds__(256) void k_colsum(const float* __restrict__ x,
                                                double* __restrict__ m)
{
  int t = threadIdx.x;
  long base = (long)blockIdx.x * 512;
  if (t < K_) {
    double s = 0.0;
    const float* p = x + base * K_ + t;
    for (int r = 0; r < 512; ++r) s += (double)p[(long)r * K_];
    atomicAdd(&m[t], s);
  }
}

// ---------------- rr = x^T x (f64 accumulate), upper tile pairs, split-K ---
__global__ __launch_bounds__(256) void k_rr(const float* __restrict__ x,
                                            double* __restrict__ rrp)
{
  int bid   = blockIdx.x;
  int split = bid % NSPLIT;
  int pair  = bid / NSPLIT;
  int bi = 0, p = pair;
  for (;;) { int cnt = 12 - bi; if (p < cnt) break; p -= cnt; ++bi; }
  int bj = bi + p;
  int tx = threadIdx.x & 15, ty = threadIdx.x >> 4;
  int i = bi * 16 + tx;
  int j = bj * 16 + ty;
  __shared__ float As[64][17], Bs[64][17];
  double acc = 0.0;
  const int chunk = N_ / NSPLIT;       // 9216
  long n0 = (long)split * chunk;
  for (int c0 = 0; c0 < chunk; c0 += 64) {
    for (int lidx = threadIdx.x; lidx < 64 * 16; lidx += 256) {
      int col = lidx & 15, row = lidx >> 4;
      long nrow = n0 + c0 + row;
      int ci = bi * 16 + col, cj = bj * 16 + col;
      As[row][col] = (ci < K_) ? x[nrow * K_ + ci] : 0.f;
      Bs[row][col] = (cj < K_) ? x[nrow * K_ + cj] : 0.f;
    }
    __syncthreads();
    #pragma unroll 8
    for (int r = 0; r < 64; ++r)
      acc += (double)As[r][tx] * (double)Bs[r][ty];
    __syncthreads();
  }
  if (i < K_ && j < K_)
    rrp[(size_t)split * K_ * K_ + (size_t)i * K_ + j] = acc;
}

// ---------------- reduce split partials -> rr (full square, LD stride) -----
__global__ __launch_bounds__(256) void k_reduce(const double* __restrict__ rrp,
                                                double* __restrict__ rr)
{
  int idx = blockIdx.x * 256 + threadIdx.x;   // packed lower-tri index
  if (idx >= TRI_N) return;
  int i = (int)((sqrtf(8.f * (float)idx + 1.f) - 1.f) * 0.5f);
  while ((i + 1) * (i + 2) / 2 <= idx) ++i;
  while (i * (i + 1) / 2 > idx) --i;
  int j = idx - (i * (i + 1)) / 2;            // j <= i
  double s = 0.0;
  for (int sp = 0; sp < NSPLIT; ++sp)
    s += rrp[(size_t)sp * K_ * K_ + (size_t)j * K_ + i];  // (row=j<=i, col=i) always written
  rr[i * LD + j] = s;
  rr[j * LD + i] = s;
}

// ---------------- LDS-resident small linear algebra ------------------------
// packed lower triangle in dynamic LDS: Cholesky -> blocked in-place trtri
// -> dii, z = rri*m -> omega/invsq/sq32, normv
__global__ __launch_bounds__(1024) void k_small2(
    const double* __restrict__ rr, const double* __restrict__ m,
    double* __restrict__ invsq, float* __restrict__ sq32,
    float* __restrict__ normv)
{
  extern __shared__ double smem[];
  double* tri = smem;               // 18336
  double* m_s = smem + TRI_N;       // 192
  double* w1  = m_s + 192;          // 192
  double* tmp = w1 + 192;           // 32*33 = 1056
  const int t = threadIdx.x;
  __shared__ double spiv;

  // load m and lower triangle of rr (+1e-6 on diag)
  if (t < K_) m_s[t] = m[t];
  for (int i = t >> 5; i < K_; i += 32) {
    int base = (i * (i + 1)) / 2;
    for (int j = t & 31; j <= i; j += 32) {
      double v = rr[i * LD + j];
      tri[base + j] = (i == j) ? v + 1e-6 : v;
    }
  }
  __syncthreads();

  // ---- Cholesky (right-looking, packed triangle in LDS) ----
  for (int k = 0; k < K_; ++k) {
    if (t == 0) {
      double d = sqrt(tri[(k * (k + 1)) / 2 + k]);
      tri[(k * (k + 1)) / 2 + k] = d; spiv = d;
    }
    __syncthreads();
    double piv = spiv;
    for (int r = k + 1 + t; r < K_; r += 1024)
      tri[(r * (r + 1)) / 2 + k] /= piv;
    __syncthreads();
    {
      int tx = t & 31, ty = t >> 5;
      for (int r = k + 1 + ty; r < K_; r += 32) {
        int rb = (r * (r + 1)) / 2;
        double lrk = tri[rb + k];
        for (int c = k + 1 + tx; c <= r; c += 32)
          tri[rb + c] -= lrk * tri[(c * (c + 1)) / 2 + k];
      }
    }
    __syncthreads();
  }

  // ---- blocked in-place trtri: tri <- X = L^{-1} ----
  // 1) diagonal blocks via tmp (each thread: own column, reads original L only)
  for (int J = 0; J < 6; ++J) {
    int j0 = J * 32;
    int nb = (K_ - j0 < 32) ? (K_ - j0) : 32;
    if (t < nb) {
      int c = t;
      for (int r = c; r < nb; ++r) {
        double s = (r == c) ? 1.0 : 0.0;
        int rb = ((j0 + r) * (j0 + r + 1)) / 2 + j0;
        for (int k = c; k < r; ++k) s -= tri[rb + k] * tmp[k * 33 + c];
        tmp[r * 33 + c] = s / tri[rb + r];
      }
    }
    __syncthreads();
    if (t < nb) {
      int c = t;
      for (int r = c; r < nb; ++r)
        tri[((j0 + r) * (j0 + r + 1)) / 2 + j0 + c] = tmp[r * 33 + c];
    }
    __syncthreads();
  }
  // 2) off-diagonal blocks, column-major: X_IJ = -X_II * (sum_K L_IK X_KJ)
  for (int J = 0; J < 5; ++J) {
    int j0 = J * 32;
    for (int I = J + 1; I < 6; ++I) {
      int i0 = I * 32;
      int nbi = (K_ - i0 < 32) ? (K_ - i0) : 32;
      int r = t & 31, c = t >> 5;
      double acc = 0.0;
      if (r < nbi) {
        int ri = i0 + r;
        int rb = (ri * (ri + 1)) / 2;
        for (int k = j0 + c; k < j0 + 32; ++k)          // X_JJ lower part
          acc += tri[rb + k] * tri[(k * (k + 1)) / 2 + j0 + c];
        for (int k = j0 + 32; k < i0; ++k)              // full X blocks below
          acc += tri[rb + k] * tri[(k * (k + 1)) / 2 + j0 + c];
      }
      tmp[r * 33 + c] = acc;
      __syncthreads();
      double out = 0.0;
      if (r < nbi) {
        int ri = i0 + r;
        int rb = (ri * (ri + 1)) / 2;
        for (int k = 0; k <= r; ++k)                    // X_II lower triangular
          out -= tri[rb + i0 + k] * tmp[k * 33 + c];
        tri[rb + j0 + c] = out;
      }
      __syncthreads();
    }
  }

  // ---- w1 = X * m (row dots) ----
  if (t < K_) {
    int r = t, rb = (r * (r + 1)) / 2;
    double s = 0.0;
    for (int p = 0; p <= r; ++p) s += tri[rb + p] * m_s[p];
    w1[r] = s;
  }
  __syncthreads();
  // ---- dii = ||X[:,i]||^2 ; z_i = (X^T w1)_i ; omega ----
  if (t < K_) {
    int i = t;
    double s2 = 0.0, s1 = 0.0;
    for (int r = i; r < K_; ++r) {
      double xv = tri[(r * (r + 1)) / 2 + i];
      s2 += xv * xv;
      s1 += xv * w1[r];
    }
    double dii = s2;
    double q = 1.0 / dii;                    // c^T rr c (1e-6 correction <=1e-9 rel, dropped)
    double sm_ = s1 / dii;
    double var = (q - sm_ * sm_ / (double)N_) / (double)(N_ - 1);
    double t1 = sqrt(var) + 1e-30;
    double om = t1 * t1;
    invsq[i] = 1.0 / sqrt(om);
    sq32[i] = sqrtf((float)om);
    tmp[i] = rr[i * LD + i] / om;            // contribution to norm_v
  }
  __syncthreads();
  if (t == 0) {
    double s = 0.0;
    for (int i = 0; i < K_; ++i) s += tmp[i];
    *normv = (float)s;
  }
}

// ---------------- G = D rr D (grid-wide) -----------------------------------
__global__ __launch_bounds__(256) void k_gw(const double* __restrict__ rr,
                                            const double* __restrict__ invsq,
                                            double* __restrict__ G)
{
  int idx = blockIdx.x * 256 + threadIdx.x;
  if (idx >= K_ * K_) return;
  int i = idx / K_, j = idx - i * K_;
  G[i * LD + j] = rr[i * LD + j] * invsq[i] * invsq[j];
}

// ---------------- one-block subspace iteration, top-32 eigenpairs of G -----
__global__ __launch_bounds__(1024) void k_sub(
    const double* __restrict__ G, double* __restrict__ Q,
    double* __restrict__ Zb, const double* __restrict__ invsq,
    const float* __restrict__ sq32, float* __restrict__ W1,
    float* __restrict__ W2)
{
  const int t = threadIdx.x;
  __shared__ double shQ[K_ * MSUB];     // 48.9 KB
  __shared__ double shS[MSUB * 33];     // 8.45 KB
  __shared__ double cs_[16], sn_[16];
  __shared__ int pp_[16], qq_[16], perm[MSUB];
  __shared__ double evals[MSUB];

  // init Q = G[:, 0:32]
  for (int idx = t; idx < K_ * MSUB; idx += 1024) {
    int i = idx >> 5, c = idx & 31;
    Q[idx] = G[(size_t)i * LD + c];
  }
  __syncthreads();

  for (int it = 0; it < 6; ++it) {
    for (int idx = t; idx < K_ * MSUB; idx += 1024) shQ[idx] = Q[idx];
    __syncthreads();
    {
      int a = t & 31, b = t >> 5;
      double s = 0.0;
      for (int r = 0; r < K_; ++r) s += shQ[r * MSUB + a] * shQ[r * MSUB + b];
      shS[b * 33 + a] = s;
    }
    __syncthreads();
    for (int k = 0; k < MSUB; ++k) {
      if (t == 0) shS[k * 33 + k] = sqrt(shS[k * 33 + k]);
      __syncthreads();
      if (t > k && t < MSUB) shS[t * 33 + k] /= shS[k * 33 + k];
      __syncthreads();
      {
        int r = t & 31, c = t >> 5;
        if (c > k && r >= c) shS[r * 33 + c] -= shS[r * 33 + k] * shS[c * 33 + k];
      }
      __syncthreads();
    }
    if (t < K_) {
      double q[MSUB];
      #pragma unroll
      for (int c = 0; c < MSUB; ++c) {
        double v = shQ[t * MSUB + c];
        for (int p = 0; p < c; ++p) v -= q[p] * shS[c * 33 + p];
        q[c] = v / shS[c * 33 + c];
      }
      #pragma unroll
      for (int c = 0; c < MSUB; ++c) { Q[t * MSUB + c] = q[c]; shQ[t * MSUB + c] = q[c]; }
    }
    __syncthreads();
    if (it < 5) {
      for (int idx = t; idx < K_ * MSUB; idx += 1024) {
        int i = idx >> 5, c = idx & 31;
        double s = 0.0;
        for (int k2 = 0; k2 < K_; ++k2) s += G[(size_t)i * LD + k2] * shQ[k2 * MSUB + c];
        Q[idx] = s;
      }
      __syncthreads();
    }
  }
  // Zb = G * Q
  for (int idx = t; idx < K_ * MSUB; idx += 1024) {
    int i = idx >> 5, c = idx & 31;
    double s = 0.0;
    for (int k2 = 0; k2 < K_; ++k2) s += G[(size_t)i * LD + k2] * shQ[k2 * MSUB + c];
    Zb[idx] = s;
  }
  __syncthreads();
  // T = Q^T Zb
  {
    int a = t & 31, b = t >> 5;
    double s = 0.0;
    for (int r = 0; r < K_; ++r) s += shQ[r * MSUB + b] * Zb[r * MSUB + a];
    shS[b * 33 + a] = s;
  }
  __syncthreads();
  // Jacobi eigensolve of 32x32 T; eigenvectors in Ws (aliases shQ)
  double* Ws = shQ;
  for (int idx = t; idx < MSUB * 33; idx += 1024) Ws[idx] = 0.0;
  __syncthreads();
  if (t < MSUB) Ws[t * 33 + t] = 1.0;
  __syncthreads();
  for (int sweep = 0; sweep < 7; ++sweep) {
    for (int round = 0; round < 31; ++round) {
      if (t < 16) {
        int ia = (t == 0) ? 0 : (1 + ((t - 1 + round) % 31));
        int ib = 1 + ((30 - t + round) % 31);
        int p = ia < ib ? ia : ib;
        int q = ia < ib ? ib : ia;
        double app = shS[p * 33 + p], aqq = shS[q * 33 + q], apq = shS[p * 33 + q];
        double c = 1.0, s = 0.0;
        if (fabs(apq) > 1e-30 * (fabs(app) + fabs(aqq)) && apq != 0.0) {
          double tau = (aqq - app) / (2.0 * apq);
          double tt = (tau >= 0.0 ? 1.0 : -1.0) / (fabs(tau) + sqrt(1.0 + tau * tau));
          c = 1.0 / sqrt(1.0 + tt * tt); s = tt * c;
        }
        cs_[t] = c; sn_[t] = s; pp_[t] = p; qq_[t] = q;
      }
      __syncthreads();
      if (t < 512) {
        int i = t & 31, mI = t >> 5;
        int p = pp_[mI], q = qq_[mI];
        double c = cs_[mI], s = sn_[mI];
        double u = shS[i * 33 + p], v = shS[i * 33 + q];
        shS[i * 33 + p] = c * u - s * v; shS[i * 33 + q] = s * u + c * v;
        double wu = Ws[i * 33 + p], wv = Ws[i * 33 + q];
        Ws[i * 33 + p] = c * wu - s * wv; Ws[i * 33 + q] = s * wu + c * wv;
      }
      __syncthreads();
      if (t < 512) {
        int j = t & 31, mI = t >> 5;
        int p = pp_[mI], q = qq_[mI];
        double c = cs_[mI], s = sn_[mI];
        double u = shS[p * 33 + j], v = shS[q * 33 + j];
        shS[p * 33 + j] = c * u - s * v; shS[q * 33 + j] = s * u + c * v;
      }
      __syncthreads();
    }
  }
  if (t == 0) {
    for (int i = 0; i < MSUB; ++i) { evals[i] = shS[i * 33 + i]; perm[i] = i; }
    for (int i = 0; i < MSUB; ++i) {
      int best = i;
      for (int j = i + 1; j < MSUB; ++j)
        if (evals[perm[j]] > evals[perm[best]]) best = j;
      int tmp2 = perm[i]; perm[i] = perm[best]; perm[best] = tmp2;
    }
  }
  __syncthreads();
  // E = Q * W (sorted); W1[k][c] = invsq_k * E ; W2[c][j] = E * sq32_j
  for (int idx = t; idx < K_ * MSUB; idx += 1024) {
    int i = idx >> 5, c = idx & 31;
    int pc_ = perm[c];
    double e = 0.0;
    for (int p = 0; p < MSUB; ++p) e += Q[i * MSUB + p] * Ws[p * 33 + pc_];
    W1[i * MSUB + c] = (float)(invsq[i] * e);
    W2[c * K_ + i]   = ((float)e) * sq32[i];
  }
}

// ---------------- pc = x * W1 (f32), channel-major output ------------------
__global__ __launch_bounds__(256) void k_pc(const float* __restrict__ x,
                                            const float* __restrict__ W1,
                                            float* __restrict__ pc)
{
  __shared__ float xs[32][192];
  __shared__ float w1s[K_ * MSUB];
  int t = threadIdx.x;
  long n0 = (long)blockIdx.x * 32;
  for (int idx = t; idx < K_ * MSUB; idx += 256) w1s[idx] = W1[idx];
  for (int idx = t; idx < 32 * K_; idx += 256) {
    int row = idx / K_, col = idx - row * K_;
    xs[row][col] = x[(n0 + row) * K_ + col];
  }
  __syncthreads();
  int c = t & 31, nl = t >> 5;
  float a0 = 0.f, a1 = 0.f, a2 = 0.f, a3 = 0.f;
  for (int k = 0; k < K_; ++k) {
    float w = w1s[k * MSUB + c];
    a0 += xs[nl][k] * w;
    a1 += xs[nl + 8][k] * w;
    a2 += xs[nl + 16][k] * w;
    a3 += xs[nl + 24][k] * w;
  }
  __syncthreads();
  float* ts = &xs[0][0];
  ts[c * 33 + nl]      = a0;
  ts[c * 33 + nl + 8]  = a1;
  ts[c * 33 + nl + 16] = a2;
  ts[c * 33 + nl + 24] = a3;
  __syncthreads();
  for (int idx = t; idx < 1024; idx += 256) {
    int cc = idx >> 5, nn = idx & 31;
    pc[(size_t)cc * N_ + n0 + nn] = ts[cc * 33 + nn];
  }
}

// ---------------- DWT: vertical analysis pass ------------------------------
__global__ __launch_bounds__(256) void k_dwtv(const float* __restrict__ in,
                                              float* __restrict__ outv, int s)
{
  long gid = (long)blockIdx.x * 256 + threadIdx.x;
  int h = s >> 1;
  long per = (long)h * s;
  if (gid >= 32 * per) return;
  int ch = (int)(gid / per);
  long rem = gid - (long)ch * per;
  int r = (int)(rem / s);
  int col = (int)(rem - (long)r * s);
  const float* cin = in + (long)ch * s * s;
  float la = 0.f, ld_ = 0.f;
  int base = 2 * r;
  #pragma unroll
  for (int l = 0; l < 10; ++l) {
    int rr_ = base + l; if (rr_ >= s) rr_ -= s;
    float v = cin[(long)rr_ * s + col];
    la += c_lo[l] * v; ld_ += c_hi[l] * v;
  }
  float* cout = outv + (long)ch * s * s;
  cout[(long)r * s + col] = la;
  cout[(long)(h + r) * s + col] = ld_;
}

// ---------------- DWT: horizontal analysis pass ----------------------------
__global__ __launch_bounds__(256) void k_dwth(const float* __restrict__ inv,
                                              float* __restrict__ llout,
                                              float* __restrict__ coef,
                                              int s, long offL, int last)
{
  long gid = (long)blockIdx.x * 256 + threadIdx.x;
  int h = s >> 1;
  long per = (long)s * h;
  if (gid >= 32 * per) return;
  int ch = (int)(gid / per);
  long rem = gid - (long)ch * per;
  int r = (int)(rem / h);
  int mcol = (int)(rem - (long)r * h);
  const float* row = inv + (long)ch * s * s + (long)r * s;
  float lo = 0.f, hi = 0.f;
  int base = 2 * mcol;
  #pragma unroll
  for (int l = 0; l < 10; ++l) {
    int cc = base + l; if (cc >= s) cc -= s;
    float v = row[cc];
    lo += c_lo[l] * v; hi += c_hi[l] * v;
  }
  float* cslab = coef + (size_t)ch * N_ + offL;
  if (r < h) {
    llout[(size_t)ch * h * h + (long)r * h + mcol] = lo;
    if (last) coef[(size_t)ch * N_ + 147312 + (long)r * h + mcol] = lo;
    cslab[(long)r * h + mcol] = hi;
  } else {
    int rd = r - h;
    cslab[(long)h * h + (long)rd * h + mcol] = lo;
    cslab[(long)2 * h * h + (long)rd * h + mcol] = hi;
  }
}

// ---------------- SURE statistics per channel ------------------------------
__global__ __launch_bounds__(256) void k_stats(const float* __restrict__ coef,
                                               float* __restrict__ stats)
{
  int ch = blockIdx.x;
  int t = threadIdx.x;
  float T2[NT];
  {
    double stop = sqrt(log(147456.0));
    double step = stop / 14.0;
    for (int i = 0; i < NT; ++i) {
      double td = (i == 14) ? stop : (double)i * step;
      float tf = (float)td;
      T2[i] = tf * tf;
    }
  }
  float cn = 0.f, sm[NT], ct[NT];
  #pragma unroll
  for (int i = 0; i < NT; ++i) { sm[i] = 0.f; ct[i] = 0.f; }
  const float* base = coef + (size_t)ch * N_;
  for (int idx = t; idx < N_; idx += 256) {
    float v = base[idx];
    float v2 = v * v;
    cn += v2;
    #pragma unroll
    for (int i = 0; i < NT; ++i) {
      sm[i] += fminf(v2, T2[i]);
      ct[i] += (v2 > T2[i]) ? 1.0f : 0.0f;
    }
  }
  __shared__ float red[256];
  for (int a = 0; a < 31; ++a) {
    float val = (a == 0) ? cn : ((a < 16) ? sm[a - 1] : ct[a - 16]);
    red[t] = val;
    __syncthreads();
    for (int off = 128; off > 0; off >>= 1) {
      if (t < off) red[t] += red[t + off];
      __syncthreads();
    }
    if (t == 0) stats[ch * 31 + a] = red[0];
    __syncthreads();
  }
}

// ---------------- SURE scan + rank -----------------------------------------
__global__ void k_rank(const float* __restrict__ stats,
                       const float* __restrict__ normv, int* __restrict__ rankp)
{
  if (threadIdx.x != 0 || blockIdx.x != 0) return;
  float c_const = *normv - 28164096.0f;
  float acc[NT];
  for (int i = 0; i < NT; ++i) acc[i] = 0.f;
  float minsure[MSUB];
  for (int r = 0; r < MSUB; ++r) {
    float cn = stats[r * 31 + 0];
    float mn = 3.4e38f;
    for (int i = 0; i < NT; ++i) {
      float sure = stats[r * 31 + 1 + i] + 2.0f * stats[r * 31 + 16 + i] - cn;
      float s_r = acc[i] + sure + c_const;
      acc[i] = acc[i] + s_r;
      if (s_r < mn) mn = s_r;
    }
    minsure[r] = mn;
  }
  int rank = -1;
  for (int r = 2; r < MSUB; ++r) {
    if (minsure[r] > minsure[r - 1]) { rank = r; break; }
  }
  if (rank < 0) rank = MSUB - 1;
  *rankp = rank;
}

// ---------------- output: out = sqrt(omega) .* (pc[:, :rank] @ vh) ---------
__global__ __launch_bounds__(256) void k_out(const float* __restrict__ pc,
                                             const float* __restrict__ W2,
                                             const int* __restrict__ rankp,
                                             float* __restrict__ out)
{
  long gid = (long)blockIdx.x * 256 + threadIdx.x;
  int n = (int)(gid / K_);
  int j = (int)(gid - (long)n * K_);
  int rank = *rankp;
  float acc = 0.f;
  for (int c = 0; c < rank; ++c)
    acc += pc[(size_t)c * N_ + n] * W2[c * K_ + j];
  out[gid] = acc;
}

extern "C" void kernel_launch(void* const* d_in, const int* in_sizes, int n_in,
                              void* d_out, int out_size, void* d_ws, size_t ws_size,
                              hipStream_t stream)
{
  if (n_in < 1 || in_sizes[0] != N_ * K_) return;
  const float* x = (const float*)d_in[0];
  float* out = (float*)d_out;
  (void)out_size;

  char* w = (char*)d_ws;
  size_t off = 0;
  auto alloc = [&](size_t bytes) -> char* {
    char* p = w + off;
    off = (off + bytes + 255) & ~(size_t)255;
    return p;
  };
  double* m_    = (double*)alloc(K_ * 8);
  double* rrp   = (double*)alloc((size_t)NSPLIT * K_ * K_ * 8);
  double* rr    = (double*)alloc((size_t)K_ * LD * 8);
  double* invsq = (double*)alloc(K_ * 8);
  float*  sq32  = (float*)alloc(K_ * 4);
  float*  normv = (float*)alloc(256);
  double* G     = (double*)alloc((size_t)K_ * LD * 8);
  double* Q     = (double*)alloc((size_t)K_ * MSUB * 8);
  double* Zb    = (double*)alloc((size_t)K_ * MSUB * 8);
  float*  W1    = (float*)alloc((size_t)K_ * MSUB * 4);
  float*  W2    = (float*)alloc((size_t)MSUB * K_ * 4);
  float*  pc    = (float*)alloc((size_t)MSUB * N_ * 4);
  float*  tmpv  = (float*)alloc((size_t)MSUB * N_ * 4);
  float*  coef  = (float*)alloc((size_t)MSUB * N_ * 4);
  float*  curA  = (float*)alloc((size_t)MSUB * 192 * 192 * 4);
  float*  curB  = (float*)alloc((size_t)MSUB * 96 * 96 * 4);
  float*  stats = (float*)alloc((size_t)MSUB * 31 * 4);
  int*    rankp = (int*)alloc(256);
  if (off > ws_size) return;

  hipMemsetAsync(m_, 0, K_ * sizeof(double), stream);

  // allow >64KB dynamic LDS for k_small2 (no-op if already permitted)
  hipFuncSetAttribute(reinterpret_cast<const void*>(k_small2),
                      hipFuncAttributeMaxDynamicSharedMemorySize, SMEM_SZ);

  k_colsum<<<N_ / 512, 256, 0, stream>>>(x, m_);
  k_rr<<<78 * NSPLIT, 256, 0, stream>>>(x, rrp);
  k_reduce<<<(TRI_N + 255) / 256, 256, 0, stream>>>(rrp, rr);
  k_small2<<<1, 1024, SMEM_SZ, stream>>>(rr, m_, invsq, sq32, normv);
  k_gw<<<(K_ * K_ + 255) / 256, 256, 0, stream>>>(rr, invsq, G);
  k_sub<<<1, 1024, 0, stream>>>(G, Q, Zb, invsq, sq32, W1, W2);
  k_pc<<<N_ / 32, 256, 0, stream>>>(x, W1, pc);

  int   sizes[5] = {384, 192, 96, 48, 24};
  long  offs[5]  = {0, 110592, 138240, 145152, 146880};
  float* lls[5]  = {curA, curB, curA, curB, curA};
  const float* curin = pc;
  for (int lev = 0; lev < 5; ++lev) {
    int s = sizes[lev], h = s >> 1;
    int nth = 32 * h * s;
    k_dwtv<<<nth / 256, 256, 0, stream>>>(curin, tmpv, s);
    k_dwth<<<nth / 256, 256, 0, stream>>>(tmpv, lls[lev], coef, s, offs[lev],
                                          lev == 4 ? 1 : 0);
    curin = lls[lev];
  }

  k_stats<<<MSUB, 256, 0, stream>>>(coef, stats);
  k_rank<<<1, 64, 0, stream>>>(stats, normv, rankp);
  k_out<<<(N_ * K_) / 256, 256, 0, stream>>>(pc, W2, rankp, out);
}

// Round 3
// 1903.648 us; speedup vs baseline: 5.7272x; 1.3686x over previous
//
#include <hip/hip_runtime.h>
#include <math.h>

#define K_     191
#define LD     192
#define N_     147456
#define MSUB   16
#define NSPLIT 16
#define NT     15
#define TRI_N  18336   // 191*192/2
#define SMEM_SZ ((TRI_N + 192 + 192 + 1056) * 8)
// k_sub dynamic LDS: 6880 doubles + 32 ints + 18336 floats
#define SMEM2_SZ (6880 * 8 + 32 * 4 + TRI_N * 4)

// db5 decomposition filters (pywt convention), f32 as in reference
__constant__ float c_lo[10] = {
  0.003335725285001549f, -0.012580751999015526f, -0.006241490213011705f,
  0.07757149384006515f,  -0.03224486958502952f, -0.24229488706619015f,
  0.13842814590110342f,   0.7243085284385744f,   0.6038292697974729f,
  0.160102397974125f };
__constant__ float c_hi[10] = {
  0.160102397974125f,    -0.6038292697974729f,   0.7243085284385744f,
 -0.13842814590110342f,  -0.24229488706619015f,  0.03224486958502952f,
  0.07757149384006515f,   0.006241490213011705f,-0.012580751999015526f,
 -0.003335725285001549f };

// ---------------- column sums of x (f64), for the regression mean ----------
__global__ __launch_bounds__(256) void k_colsum(const float* __restrict__ x,
                                                double* __restrict__ m)
{
  int t = threadIdx.x;
  long base = (long)blockIdx.x * 512;
  if (t < K_) {
    double s = 0.0;
    const float* p = x + base * K_ + t;
    for (int r = 0; r < 512; ++r) s += (double)p[(long)r * K_];
    atomicAdd(&m[t], s);
  }
}

// ---------------- rr = x^T x (f64 accumulate), upper tile pairs, split-K ---
__global__ __launch_bounds__(256) void k_rr(const float* __restrict__ x,
                                            double* __restrict__ rrp)
{
  int bid   = blockIdx.x;
  int split = bid % NSPLIT;
  int pair  = bid / NSPLIT;
  int bi = 0, p = pair;
  for (;;) { int cnt = 12 - bi; if (p < cnt) break; p -= cnt; ++bi; }
  int bj = bi + p;
  int tx = threadIdx.x & 15, ty = threadIdx.x >> 4;
  int i = bi * 16 + tx;
  int j = bj * 16 + ty;
  __shared__ float As[64][17], Bs[64][17];
  double acc = 0.0;
  const int chunk = N_ / NSPLIT;       // 9216
  long n0 = (long)split * chunk;
  for (int c0 = 0; c0 < chunk; c0 += 64) {
    for (int lidx = threadIdx.x; lidx < 64 * 16; lidx += 256) {
      int col = lidx & 15, row = lidx >> 4;
      long nrow = n0 + c0 + row;
      int ci = bi * 16 + col, cj = bj * 16 + col;
      As[row][col] = (ci < K_) ? x[nrow * K_ + ci] : 0.f;
      Bs[row][col] = (cj < K_) ? x[nrow * K_ + cj] : 0.f;
    }
    __syncthreads();
    #pragma unroll 8
    for (int r = 0; r < 64; ++r)
      acc += (double)As[r][tx] * (double)Bs[r][ty];
    __syncthreads();
  }
  if (i < K_ && j < K_)
    rrp[(size_t)split * K_ * K_ + (size_t)i * K_ + j] = acc;
}

// ---------------- reduce split partials -> rr (full square, LD stride) -----
__global__ __launch_bounds__(256) void k_reduce(const double* __restrict__ rrp,
                                                double* __restrict__ rr)
{
  int idx = blockIdx.x * 256 + threadIdx.x;   // packed lower-tri index
  if (idx >= TRI_N) return;
  int i = (int)((sqrtf(8.f * (float)idx + 1.f) - 1.f) * 0.5f);
  while ((i + 1) * (i + 2) / 2 <= idx) ++i;
  while (i * (i + 1) / 2 > idx) --i;
  int j = idx - (i * (i + 1)) / 2;            // j <= i
  double s = 0.0;
  for (int sp = 0; sp < NSPLIT; ++sp)
    s += rrp[(size_t)sp * K_ * K_ + (size_t)j * K_ + i];
  rr[i * LD + j] = s;
  rr[j * LD + i] = s;
}

// ---------------- LDS-resident small linear algebra ------------------------
__global__ __launch_bounds__(1024) void k_small2(
    const double* __restrict__ rr, const double* __restrict__ m,
    double* __restrict__ invsq, float* __restrict__ sq32,
    float* __restrict__ normv)
{
  extern __shared__ double smem[];
  double* tri = smem;               // 18336
  double* m_s = smem + TRI_N;       // 192
  double* w1  = m_s + 192;          // 192
  double* tmp = w1 + 192;           // 32*33 = 1056
  const int t = threadIdx.x;
  __shared__ double spiv;

  if (t < K_) m_s[t] = m[t];
  for (int i = t >> 5; i < K_; i += 32) {
    int base = (i * (i + 1)) / 2;
    for (int j = t & 31; j <= i; j += 32) {
      double v = rr[i * LD + j];
      tri[base + j] = (i == j) ? v + 1e-6 : v;
    }
  }
  __syncthreads();

  // Cholesky (right-looking, packed triangle in LDS)
  for (int k = 0; k < K_; ++k) {
    if (t == 0) {
      double d = sqrt(tri[(k * (k + 1)) / 2 + k]);
      tri[(k * (k + 1)) / 2 + k] = d; spiv = d;
    }
    __syncthreads();
    double piv = spiv;
    for (int r = k + 1 + t; r < K_; r += 1024)
      tri[(r * (r + 1)) / 2 + k] /= piv;
    __syncthreads();
    {
      int tx = t & 31, ty = t >> 5;
      for (int r = k + 1 + ty; r < K_; r += 32) {
        int rb = (r * (r + 1)) / 2;
        double lrk = tri[rb + k];
        for (int c = k + 1 + tx; c <= r; c += 32)
          tri[rb + c] -= lrk * tri[(c * (c + 1)) / 2 + k];
      }
    }
    __syncthreads();
  }

  // blocked in-place trtri: tri <- X = L^{-1}
  for (int J = 0; J < 6; ++J) {
    int j0 = J * 32;
    int nb = (K_ - j0 < 32) ? (K_ - j0) : 32;
    if (t < nb) {
      int c = t;
      for (int r = c; r < nb; ++r) {
        double s = (r == c) ? 1.0 : 0.0;
        int rb = ((j0 + r) * (j0 + r + 1)) / 2 + j0;
        for (int k = c; k < r; ++k) s -= tri[rb + k] * tmp[k * 33 + c];
        tmp[r * 33 + c] = s / tri[rb + r];
      }
    }
    __syncthreads();
    if (t < nb) {
      int c = t;
      for (int r = c; r < nb; ++r)
        tri[((j0 + r) * (j0 + r + 1)) / 2 + j0 + c] = tmp[r * 33 + c];
    }
    __syncthreads();
  }
  for (int J = 0; J < 5; ++J) {
    int j0 = J * 32;
    for (int I = J + 1; I < 6; ++I) {
      int i0 = I * 32;
      int nbi = (K_ - i0 < 32) ? (K_ - i0) : 32;
      int r = t & 31, c = t >> 5;
      double acc = 0.0;
      if (r < nbi) {
        int ri = i0 + r;
        int rb = (ri * (ri + 1)) / 2;
        for (int k = j0 + c; k < j0 + 32; ++k)
          acc += tri[rb + k] * tri[(k * (k + 1)) / 2 + j0 + c];
        for (int k = j0 + 32; k < i0; ++k)
          acc += tri[rb + k] * tri[(k * (k + 1)) / 2 + j0 + c];
      }
      tmp[r * 33 + c] = acc;
      __syncthreads();
      double out = 0.0;
      if (r < nbi) {
        int ri = i0 + r;
        int rb = (ri * (ri + 1)) / 2;
        for (int k = 0; k <= r; ++k)
          out -= tri[rb + i0 + k] * tmp[k * 33 + c];
        tri[rb + j0 + c] = out;
      }
      __syncthreads();
    }
  }

  if (t < K_) {
    int r = t, rb = (r * (r + 1)) / 2;
    double s = 0.0;
    for (int p = 0; p <= r; ++p) s += tri[rb + p] * m_s[p];
    w1[r] = s;
  }
  __syncthreads();
  if (t < K_) {
    int i = t;
    double s2 = 0.0, s1 = 0.0;
    for (int r = i; r < K_; ++r) {
      double xv = tri[(r * (r + 1)) / 2 + i];
      s2 += xv * xv;
      s1 += xv * w1[r];
    }
    double dii = s2;
    double q = 1.0 / dii;
    double sm_ = s1 / dii;
    double var = (q - sm_ * sm_ / (double)N_) / (double)(N_ - 1);
    double t1 = sqrt(var) + 1e-30;
    double om = t1 * t1;
    invsq[i] = 1.0 / sqrt(om);
    sq32[i] = sqrtf((float)om);
    tmp[i] = rr[i * LD + i] / om;
  }
  __syncthreads();
  if (t == 0) {
    double s = 0.0;
    for (int i = 0; i < K_; ++i) s += tmp[i];
    *normv = (float)s;
  }
}

// ---------------- CholQR helper (operates on shQ K_ x MSUB, shS MSUB x 17) -
__device__ __forceinline__ void cholqr(double* shQ, double* shS, int t)
{
  // S = Q^T Q
  if (t < MSUB * MSUB) {
    int a = t & (MSUB - 1), b = t >> 4;
    double s = 0.0;
    for (int r = 0; r < K_; ++r) s += shQ[r * MSUB + a] * shQ[r * MSUB + b];
    shS[b * 17 + a] = s;
  }
  __syncthreads();
  // Cholesky 16x16 (lower)
  for (int k = 0; k < MSUB; ++k) {
    if (t == 0) shS[k * 17 + k] = sqrt(shS[k * 17 + k]);
    __syncthreads();
    if (t > k && t < MSUB) shS[t * 17 + k] /= shS[k * 17 + k];
    __syncthreads();
    if (t < MSUB * MSUB) {
      int r = t & (MSUB - 1), c = t >> 4;
      if (c > k && r >= c) shS[r * 17 + c] -= shS[r * 17 + k] * shS[c * 17 + k];
    }
    __syncthreads();
  }
  // rows solve: Qnew L^T = Qold
  if (t < K_) {
    double q[MSUB];
    #pragma unroll
    for (int c = 0; c < MSUB; ++c) {
      double v = shQ[t * MSUB + c];
      for (int p = 0; p < c; ++p) v -= q[p] * shS[c * 17 + p];
      q[c] = v / shS[c * 17 + c];
    }
    #pragma unroll
    for (int c = 0; c < MSUB; ++c) shQ[t * MSUB + c] = q[c];
  }
  __syncthreads();
}

// ---------------- one-block subspace iteration, top-16 eigenpairs ----------
// G = D rr D staged as packed f32 lower triangle in LDS; all else f64 LDS.
__global__ __launch_bounds__(512) void k_sub(
    const double* __restrict__ rr, const double* __restrict__ invsq,
    float* __restrict__ W1, float* __restrict__ W2)
{
  extern __shared__ double dsm[];
  double* shQ  = dsm;                 // 3056
  double* shZ  = shQ + 3056;          // 3056
  double* shS  = shZ + 3056;          // 272 (16*17)
  double* Ws   = shS + 272;           // 272
  double* inv_s= Ws + 272;            // 192
  double* ev   = inv_s + 192;         // 16
  double* cs_  = ev + 16;             // 8
  double* sn_  = cs_ + 8;             // 8
  int* ipp  = (int*)(sn_ + 8);        // 8
  int* iqq  = ipp + 8;                // 8
  int* perm = iqq + 8;                // 16
  float* tri = (float*)(perm + 16);   // 18336
  const int t = threadIdx.x;

  if (t < K_) inv_s[t] = invsq[t];
  __syncthreads();
  // stage G lower triangle (f32): G_ij = rr_ij * invsq_i * invsq_j
  for (int i = t >> 4; i < K_; i += 32) {
    int base = (i * (i + 1)) / 2;
    double di = inv_s[i];
    for (int j = t & 15; j <= i; j += 16)
      tri[base + j] = (float)(rr[i * LD + j] * di * inv_s[j]);
  }
  __syncthreads();

  // init Q = G[:, 0:16]
  for (int idx = t; idx < K_ * MSUB; idx += 512) {
    int i = idx >> 4, c = idx & 15;
    float g = (i >= c) ? tri[(i * (i + 1)) / 2 + c] : tri[(c * (c + 1)) / 2 + i];
    shQ[idx] = (double)g;
  }
  __syncthreads();

  cholqr(shQ, shS, t);
  for (int it = 0; it < 4; ++it) {
    // copy Q -> Z
    for (int idx = t; idx < K_ * MSUB; idx += 512) shZ[idx] = shQ[idx];
    __syncthreads();
    // Q = G * Z   (triangular-packed G)
    for (int idx = t; idx < K_ * MSUB; idx += 512) {
      int i = idx >> 4, c = idx & 15;
      double s = 0.0;
      int rb = (i * (i + 1)) >> 1;
      for (int k = 0; k <= i; ++k) s += (double)tri[rb + k] * shZ[k * MSUB + c];
      int kk = ((i + 1) * (i + 2)) >> 1;
      for (int k = i + 1; k < K_; ++k) { s += (double)tri[kk + i] * shZ[k * MSUB + c]; kk += k + 1; }
      shQ[idx] = s;
    }
    __syncthreads();
    if (it < 3) cholqr(shQ, shS, t);
  }
  // here: shZ = Q_orth, shQ = G*Q_orth.  T = Z^T Q  -> shS
  if (t < MSUB * MSUB) {
    int a = t & 15, b = t >> 4;
    double s = 0.0;
    for (int r = 0; r < K_; ++r) s += shZ[r * MSUB + b] * shQ[r * MSUB + a];
    shS[b * 17 + a] = s;
  }
  // init Ws = I
  if (t < MSUB * 17) Ws[t] = 0.0;
  __syncthreads();
  if (t < MSUB) Ws[t * 17 + t] = 1.0;
  __syncthreads();
  // Jacobi eigensolve of 16x16 T
  for (int sweep = 0; sweep < 6; ++sweep) {
    for (int round = 0; round < 15; ++round) {
      if (t < 8) {
        int ia = (t == 0) ? 0 : (1 + ((t - 1 + round) % 15));
        int ib = 1 + ((14 - t + round) % 15);
        int p = ia < ib ? ia : ib;
        int q = ia < ib ? ib : ia;
        double app = shS[p * 17 + p], aqq = shS[q * 17 + q], apq = shS[p * 17 + q];
        double c = 1.0, s = 0.0;
        if (fabs(apq) > 1e-30 * (fabs(app) + fabs(aqq)) && apq != 0.0) {
          double tau = (aqq - app) / (2.0 * apq);
          double tt = (tau >= 0.0 ? 1.0 : -1.0) / (fabs(tau) + sqrt(1.0 + tau * tau));
          c = 1.0 / sqrt(1.0 + tt * tt); s = tt * c;
        }
        cs_[t] = c; sn_[t] = s; ipp[t] = p; iqq[t] = q;
      }
      __syncthreads();
      if (t < 128) {   // column rotations of T and Ws
        int i = t & 15, mI = t >> 4;
        int p = ipp[mI], q = iqq[mI];
        double c = cs_[mI], s = sn_[mI];
        double u = shS[i * 17 + p], v = shS[i * 17 + q];
        shS[i * 17 + p] = c * u - s * v; shS[i * 17 + q] = s * u + c * v;
        double wu = Ws[i * 17 + p], wv = Ws[i * 17 + q];
        Ws[i * 17 + p] = c * wu - s * wv; Ws[i * 17 + q] = s * wu + c * wv;
      }
      __syncthreads();
      if (t < 128) {   // row rotations of T
        int j = t & 15, mI = t >> 4;
        int p = ipp[mI], q = iqq[mI];
        double c = cs_[mI], s = sn_[mI];
        double u = shS[p * 17 + j], v = shS[q * 17 + j];
        shS[p * 17 + j] = c * u - s * v; shS[q * 17 + j] = s * u + c * v;
      }
      __syncthreads();
    }
  }
  if (t == 0) {
    for (int i = 0; i < MSUB; ++i) { ev[i] = shS[i * 17 + i]; perm[i] = i; }
    for (int i = 0; i < MSUB; ++i) {
      int best = i;
      for (int j = i + 1; j < MSUB; ++j)
        if (ev[perm[j]] > ev[perm[best]]) best = j;
      int tp = perm[i]; perm[i] = perm[best]; perm[best] = tp;
    }
  }
  __syncthreads();
  // E = Q_orth * Ws (sorted); W1[i][c] = invsq_i * E ; W2[c][i] = E * sqrt(om_i)
  for (int idx = t; idx < K_ * MSUB; idx += 512) {
    int i = idx >> 4, c = idx & 15;
    int pc_ = perm[c];
    double e = 0.0;
    #pragma unroll
    for (int p = 0; p < MSUB; ++p) e += shZ[i * MSUB + p] * Ws[p * 17 + pc_];
    W1[i * MSUB + c] = (float)(inv_s[i] * e);
    W2[c * K_ + i]   = (float)(e / inv_s[i]);
  }
}

// ---------------- pc = x * W1 (f32), channel-major output ------------------
__global__ __launch_bounds__(256) void k_pc(const float* __restrict__ x,
                                            const float* __restrict__ W1,
                                            float* __restrict__ pc)
{
  __shared__ float xs[32][192];
  __shared__ float w1s[K_ * MSUB];
  int t = threadIdx.x;
  long n0 = (long)blockIdx.x * 32;
  for (int idx = t; idx < K_ * MSUB; idx += 256) w1s[idx] = W1[idx];
  for (int idx = t; idx < 32 * K_; idx += 256) {
    int row = idx / K_, col = idx - row * K_;
    xs[row][col] = x[(n0 + row) * K_ + col];
  }
  __syncthreads();
  int c = t & 15, nl = t >> 4;         // nl in [0,16)
  float a0 = 0.f, a1 = 0.f;
  for (int k = 0; k < K_; ++k) {
    float w = w1s[k * MSUB + c];
    a0 += xs[nl][k] * w;
    a1 += xs[nl + 16][k] * w;
  }
  __syncthreads();
  float* ts = &xs[0][0];               // reuse as 16x33 transpose buffer
  ts[c * 33 + nl]      = a0;
  ts[c * 33 + nl + 16] = a1;
  __syncthreads();
  for (int idx = t; idx < MSUB * 32; idx += 256) {
    int cc = idx >> 5, nn = idx & 31;
    pc[(size_t)cc * N_ + n0 + nn] = ts[cc * 33 + nn];
  }
}

// ---------------- DWT: vertical analysis pass ------------------------------
__global__ __launch_bounds__(256) void k_dwtv(const float* __restrict__ in,
                                              float* __restrict__ outv, int s)
{
  long gid = (long)blockIdx.x * 256 + threadIdx.x;
  int h = s >> 1;
  long per = (long)h * s;
  if (gid >= MSUB * per) return;
  int ch = (int)(gid / per);
  long rem = gid - (long)ch * per;
  int r = (int)(rem / s);
  int col = (int)(rem - (long)r * s);
  const float* cin = in + (long)ch * s * s;
  float la = 0.f, ld_ = 0.f;
  int base = 2 * r;
  #pragma unroll
  for (int l = 0; l < 10; ++l) {
    int rr_ = base + l; if (rr_ >= s) rr_ -= s;
    float v = cin[(long)rr_ * s + col];
    la += c_lo[l] * v; ld_ += c_hi[l] * v;
  }
  float* cout = outv + (long)ch * s * s;
  cout[(long)r * s + col] = la;
  cout[(long)(h + r) * s + col] = ld_;
}

// ---------------- DWT: horizontal analysis pass ----------------------------
__global__ __launch_bounds__(256) void k_dwth(const float* __restrict__ inv,
                                              float* __restrict__ llout,
                                              float* __restrict__ coef,
                                              int s, long offL, int last)
{
  long gid = (long)blockIdx.x * 256 + threadIdx.x;
  int h = s >> 1;
  long per = (long)s * h;
  if (gid >= MSUB * per) return;
  int ch = (int)(gid / per);
  long rem = gid - (long)ch * per;
  int r = (int)(rem / h);
  int mcol = (int)(rem - (long)r * h);
  const float* row = inv + (long)ch * s * s + (long)r * s;
  float lo = 0.f, hi = 0.f;
  int base = 2 * mcol;
  #pragma unroll
  for (int l = 0; l < 10; ++l) {
    int cc = base + l; if (cc >= s) cc -= s;
    float v = row[cc];
    lo += c_lo[l] * v; hi += c_hi[l] * v;
  }
  float* cslab = coef + (size_t)ch * N_ + offL;
  if (r < h) {
    llout[(size_t)ch * h * h + (long)r * h + mcol] = lo;
    if (last) coef[(size_t)ch * N_ + 147312 + (long)r * h + mcol] = lo;
    cslab[(long)r * h + mcol] = hi;
  } else {
    int rd = r - h;
    cslab[(long)h * h + (long)rd * h + mcol] = lo;
    cslab[(long)2 * h * h + (long)rd * h + mcol] = hi;
  }
}

// ---------------- SURE statistics per channel ------------------------------
__global__ __launch_bounds__(256) void k_stats(const float* __restrict__ coef,
                                               float* __restrict__ stats)
{
  int ch = blockIdx.x;
  int t = threadIdx.x;
  float T2[NT];
  {
    double stop = sqrt(log(147456.0));
    double step = stop / 14.0;
    for (int i = 0; i < NT; ++i) {
      double td = (i == 14) ? stop : (double)i * step;
      float tf = (float)td;
      T2[i] = tf * tf;
    }
  }
  float cn = 0.f, sm[NT], ct[NT];
  #pragma unroll
  for (int i = 0; i < NT; ++i) { sm[i] = 0.f; ct[i] = 0.f; }
  const float* base = coef + (size_t)ch * N_;
  for (int idx = t; idx < N_; idx += 256) {
    float v = base[idx];
    float v2 = v * v;
    cn += v2;
    #pragma unroll
    for (int i = 0; i < NT; ++i) {
      sm[i] += fminf(v2, T2[i]);
      ct[i] += (v2 > T2[i]) ? 1.0f : 0.0f;
    }
  }
  __shared__ float red[256];
  for (int a = 0; a < 31; ++a) {
    float val = (a == 0) ? cn : ((a < 16) ? sm[a - 1] : ct[a - 16]);
    red[t] = val;
    __syncthreads();
    for (int off = 128; off > 0; off >>= 1) {
      if (t < off) red[t] += red[t + off];
      __syncthreads();
    }
    if (t == 0) stats[ch * 31 + a] = red[0];
    __syncthreads();
  }
}

// ---------------- SURE scan + rank -----------------------------------------
__global__ void k_rank(const float* __restrict__ stats,
                       const float* __restrict__ normv, int* __restrict__ rankp)
{
  if (threadIdx.x != 0 || blockIdx.x != 0) return;
  float c_const = *normv - 28164096.0f;
  float acc[NT];
  for (int i = 0; i < NT; ++i) acc[i] = 0.f;
  float minsure[MSUB];
  for (int r = 0; r < MSUB; ++r) {
    float cn = stats[r * 31 + 0];
    float mn = 3.4e38f;
    for (int i = 0; i < NT; ++i) {
      float sure = stats[r * 31 + 1 + i] + 2.0f * stats[r * 31 + 16 + i] - cn;
      float s_r = acc[i] + sure + c_const;
      acc[i] = acc[i] + s_r;
      if (s_r < mn) mn = s_r;
    }
    minsure[r] = mn;
  }
  int rank = -1;
  for (int r = 2; r < MSUB; ++r) {
    if (minsure[r] > minsure[r - 1]) { rank = r; break; }
  }
  if (rank < 0) rank = MSUB - 1;
  *rankp = rank;
}

// ---------------- output: out = sqrt(omega) .* (pc[:, :rank] @ vh) ---------
__global__ __launch_bounds__(256) void k_out(const float* __restrict__ pc,
                                             const float* __restrict__ W2,
                                             const int* __restrict__ rankp,
                                             float* __restrict__ out)
{
  long gid = (long)blockIdx.x * 256 + threadIdx.x;
  int n = (int)(gid / K_);
  int j = (int)(gid - (long)n * K_);
  int rank = *rankp;
  float acc = 0.f;
  for (int c = 0; c < rank; ++c)
    acc += pc[(size_t)c * N_ + n] * W2[c * K_ + j];
  out[gid] = acc;
}

extern "C" void kernel_launch(void* const* d_in, const int* in_sizes, int n_in,
                              void* d_out, int out_size, void* d_ws, size_t ws_size,
                              hipStream_t stream)
{
  if (n_in < 1 || in_sizes[0] != N_ * K_) return;
  const float* x = (const float*)d_in[0];
  float* out = (float*)d_out;
  (void)out_size;

  char* w = (char*)d_ws;
  size_t off = 0;
  auto alloc = [&](size_t bytes) -> char* {
    char* p = w + off;
    off = (off + bytes + 255) & ~(size_t)255;
    return p;
  };
  double* m_    = (double*)alloc(K_ * 8);
  double* rrp   = (double*)alloc((size_t)NSPLIT * K_ * K_ * 8);
  double* rr    = (double*)alloc((size_t)K_ * LD * 8);
  double* invsq = (double*)alloc(K_ * 8);
  float*  sq32  = (float*)alloc(K_ * 4);
  float*  normv = (float*)alloc(256);
  float*  W1    = (float*)alloc((size_t)K_ * MSUB * 4);
  float*  W2    = (float*)alloc((size_t)MSUB * K_ * 4);
  float*  pc    = (float*)alloc((size_t)MSUB * N_ * 4);
  float*  tmpv  = (float*)alloc((size_t)MSUB * N_ * 4);
  float*  coef  = (float*)alloc((size_t)MSUB * N_ * 4);
  float*  curA  = (float*)alloc((size_t)MSUB * 192 * 192 * 4);
  float*  curB  = (float*)alloc((size_t)MSUB * 96 * 96 * 4);
  float*  stats = (float*)alloc((size_t)MSUB * 31 * 4);
  int*    rankp = (int*)alloc(256);
  if (off > ws_size) return;

  hipMemsetAsync(m_, 0, K_ * sizeof(double), stream);

  hipFuncSetAttribute(reinterpret_cast<const void*>(k_small2),
                      hipFuncAttributeMaxDynamicSharedMemorySize, SMEM_SZ);
  hipFuncSetAttribute(reinterpret_cast<const void*>(k_sub),
                      hipFuncAttributeMaxDynamicSharedMemorySize, SMEM2_SZ);

  k_colsum<<<N_ / 512, 256, 0, stream>>>(x, m_);
  k_rr<<<78 * NSPLIT, 256, 0, stream>>>(x, rrp);
  k_reduce<<<(TRI_N + 255) / 256, 256, 0, stream>>>(rrp, rr);
  k_small2<<<1, 1024, SMEM_SZ, stream>>>(rr, m_, invsq, sq32, normv);
  k_sub<<<1, 512, SMEM2_SZ, stream>>>(rr, invsq, W1, W2);
  k_pc<<<N_ / 32, 256, 0, stream>>>(x, W1, pc);

  int   sizes[5] = {384, 192, 96, 48, 24};
  long  offs[5]  = {0, 110592, 138240, 145152, 146880};
  float* lls[5]  = {curA, curB, curA, curB, curA};
  const float* curin = pc;
  for (int lev = 0; lev < 5; ++lev) {
    int s = sizes[lev], h = s >> 1;
    long nth = (long)MSUB * h * s;
    k_dwtv<<<(int)((nth + 255) / 256), 256, 0, stream>>>(curin, tmpv, s);
    k_dwth<<<(int)((nth + 255) / 256), 256, 0, stream>>>(tmpv, lls[lev], coef,
                                                         s, offs[lev],
                                                         lev == 4 ? 1 : 0);
    curin = lls[lev];
  }

  k_stats<<<MSUB, 256, 0, stream>>>(coef, stats);
  k_rank<<<1, 64, 0, stream>>>(stats, normv, rankp);
  k_out<<<(N_ * K_) / 256, 256, 0, stream>>>(pc, W2, rankp, out);
}